// Round 3
// baseline (257.165 us; speedup 1.0000x reference)
//
#include <hip/hip_runtime.h>

typedef unsigned short u16;
typedef unsigned int u32;
typedef short bf16x8 __attribute__((ext_vector_type(8)));
typedef float f32x4 __attribute__((ext_vector_type(4)));
typedef u16 u16x8 __attribute__((ext_vector_type(8)));
typedef u16 u16x4 __attribute__((ext_vector_type(4)));

typedef const __attribute__((address_space(1))) u32* gas_ptr;
typedef __attribute__((address_space(3))) u32* las_ptr;

#define LQ   4096
#define EMB  512
#define NB   4
#define MROWS (NB * LQ)            // 16384
#define QSCALE 0.04419417382415922f // 1/sqrt(512)

__device__ __forceinline__ u16 f2bf(float f) {
  unsigned u = __builtin_bit_cast(unsigned, f);
  u += 0x7fffu + ((u >> 16) & 1u);
  return (u16)(u >> 16);
}
__device__ __forceinline__ float bf2f(u16 h) {
  unsigned u = ((unsigned)h) << 16;
  return __builtin_bit_cast(float, u);
}

// ---------------- prep ----------------------------------------------------
__global__ void prep_w(const float* __restrict__ Wq, const float* __restrict__ bq,
                       const float* __restrict__ Wk, const float* __restrict__ bk,
                       const float* __restrict__ Wv, const float* __restrict__ bv,
                       u16* __restrict__ wqb, u16* __restrict__ wkb, u16* __restrict__ wvb,
                       float* __restrict__ bias) {
  int i = blockIdx.x * 256 + threadIdx.x;
  if (i < EMB * EMB) {
    wqb[i] = f2bf(Wq[i] * QSCALE);
    wkb[i] = f2bf(Wk[i]);
    wvb[i] = f2bf(Wv[i]);
  }
  if (i < EMB) {
    bias[i]           = bq[i] * QSCALE;
    bias[EMB + i]     = bk[i];
    bias[2 * EMB + i] = bv[i];
  }
}

__global__ void prep_x(const float* __restrict__ x, u16* __restrict__ xb) {
  int i = blockIdx.x * 256 + threadIdx.x;
  const float4* p = (const float4*)(x + (size_t)i * 8);
  float4 a = p[0], b = p[1];
  u16x8 o;
  o[0] = f2bf(a.x); o[1] = f2bf(a.y); o[2] = f2bf(a.z); o[3] = f2bf(a.w);
  o[4] = f2bf(b.x); o[5] = f2bf(b.y); o[6] = f2bf(b.z); o[7] = f2bf(b.w);
  *(u16x8*)(xb + (size_t)i * 8) = o;
}

// ---- stage one 128x64 bf16 tile (16KB) with 256 threads, gload_lds w=16 ---
// Linear LDS dest + inverse-XOR-swizzled global source (rule #21).
__device__ __forceinline__ void stage128_256t(const u16* g, int ld, u16* lds, int tid) {
  int wave = tid >> 6;
#pragma unroll
  for (int p = 0; p < 4; ++p) {
    int c = tid + p * 256;           // chunk 0..1023
    int row = c >> 3, hh = c & 7;
    int h = hh ^ (row & 7);
    const u16* src = g + (size_t)row * ld + h * 8;
    u16* dst = lds + wave * 512 + p * 2048;   // wave-uniform base, lane*16B auto
    __builtin_amdgcn_global_load_lds((gas_ptr)(const void*)src, (las_ptr)(void*)dst, 16, 0, 0);
  }
}

// ---- 128x128 GEMM core, dbuf + prefetch: sync -> stage(next) -> compute ---
// lds: [2 bufs][A 8192 u16 | B 8192 u16] = 32768 u16 = 64KB
__device__ __forceinline__ void gemm_core_db(
    const u16* __restrict__ A, int lda,
    const u16* __restrict__ B, int ldb,
    int kIters, u16* lds,
    f32x4 acc[4][4], int tid, int lane, int wr, int wc)
{
  stage128_256t(A, lda, lds, tid);
  stage128_256t(B, ldb, lds + 8192, tid);
  for (int kb = 0; kb < kIters; ++kb) {
    u16* ldsA = lds + (kb & 1) * 16384;
    u16* ldsB = ldsA + 8192;
    __syncthreads();                 // drains prev-issued stage (latency hidden by prev compute)
    if (kb + 1 < kIters) {
      u16* nA = lds + ((kb + 1) & 1) * 16384;
      stage128_256t(A + (kb + 1) * 64, lda, nA, tid);
      stage128_256t(B + (kb + 1) * 64, ldb, nA + 8192, tid);
    }
#pragma unroll
    for (int s = 0; s < 2; ++s) {
      bf16x8 af[4], bfr[4];
#pragma unroll
      for (int m = 0; m < 4; ++m) {
        int row = wr * 64 + m * 16 + (lane & 15);
        int hh = (s * 4 + (lane >> 4)) ^ (row & 7);
        af[m] = *(const bf16x8*)(ldsA + row * 64 + hh * 8);
      }
#pragma unroll
      for (int n = 0; n < 4; ++n) {
        int row = wc * 64 + n * 16 + (lane & 15);
        int hh = (s * 4 + (lane >> 4)) ^ (row & 7);
        bfr[n] = *(const bf16x8*)(ldsB + row * 64 + hh * 8);
      }
#pragma unroll
      for (int m = 0; m < 4; ++m)
#pragma unroll
        for (int n = 0; n < 4; ++n)
          acc[m][n] = __builtin_amdgcn_mfma_f32_16x16x32_bf16(af[m], bfr[n], acc[m][n], 0, 0, 0);
    }
  }
}

// ---------------- K1: fused QKV projection GEMM --------------------------
__global__ __launch_bounds__(256, 2) void k_qkv(
    const u16* __restrict__ xb,
    const u16* __restrict__ w0, const u16* __restrict__ w1, const u16* __restrict__ w2,
    const float* __restrict__ bias,
    u16* __restrict__ o0, u16* __restrict__ o1, u16* __restrict__ o2)
{
  __shared__ __align__(16) u16 lds[32768];
  int bi = blockIdx.x;
  int which = bi >> 9;
  int t = bi & 511;
  int rt = t >> 2, ct = t & 3;
  const u16* W = (which == 0) ? w0 : (which == 1) ? w1 : w2;
  const float* bs = bias + which * EMB;
  int tid = threadIdx.x, lane = tid & 63, wave = tid >> 6;
  int wr = wave >> 1, wc = wave & 1;
  f32x4 acc[4][4];
#pragma unroll
  for (int m = 0; m < 4; ++m)
#pragma unroll
    for (int n = 0; n < 4; ++n) acc[m][n] = (f32x4)0.0f;

  gemm_core_db(xb + (size_t)rt * 128 * EMB, EMB,
               W + (size_t)ct * 128 * EMB, EMB, EMB / 64,
               lds, acc, tid, lane, wr, wc);

#pragma unroll
  for (int m = 0; m < 4; ++m)
#pragma unroll
    for (int n = 0; n < 4; ++n) {
      int row0 = rt * 128 + wr * 64 + m * 16 + ((lane >> 4) << 2);
      int col  = ct * 128 + wc * 64 + n * 16 + (lane & 15);
      float bv = bs[col];
      if (which < 2) {
        u16* out = (which == 0) ? o0 : o1;
#pragma unroll
        for (int r = 0; r < 4; ++r)
          out[(size_t)(row0 + r) * EMB + col] = f2bf(acc[m][n][r] + bv);
      } else {
        int b = row0 >> 12, l0 = row0 & (LQ - 1);
        u16x4 pk;
#pragma unroll
        for (int r = 0; r < 4; ++r) pk[r] = f2bf(acc[m][n][r] + bv);
        *(u16x4*)(o2 + ((size_t)(b * EMB + col)) * LQ + l0) = pk;
      }
    }
}

// ---------------- K2: S = Q K^T on causal (lower-tri) tiles --------------
__global__ __launch_bounds__(256, 2) void k_qk(
    const u16* __restrict__ Q, const u16* __restrict__ K,
    u16* __restrict__ S, int bstart)
{
  __shared__ __align__(16) u16 lds[32768];
  int t = blockIdx.x;
  int b_local = t / 528;
  int i = t - b_local * 528;
  int qi = (int)((sqrtf(8.f * (float)i + 1.f) - 1.f) * 0.5f);
  while ((qi + 1) * (qi + 2) / 2 <= i) ++qi;
  while (qi * (qi + 1) / 2 > i) --qi;
  int ki = i - qi * (qi + 1) / 2;
  int bg = bstart + b_local;

  int tid = threadIdx.x, lane = tid & 63, wave = tid >> 6;
  int wr = wave >> 1, wc = wave & 1;
  f32x4 acc[4][4];
#pragma unroll
  for (int m = 0; m < 4; ++m)
#pragma unroll
    for (int n = 0; n < 4; ++n) acc[m][n] = (f32x4)0.0f;

  gemm_core_db(Q + ((size_t)bg * LQ + qi * 128) * EMB, EMB,
               K + ((size_t)bg * LQ + ki * 128) * EMB, EMB, EMB / 64,
               lds, acc, tid, lane, wr, wc);

  u16* Sb = S + (size_t)b_local * LQ * LQ;
#pragma unroll
  for (int m = 0; m < 4; ++m)
#pragma unroll
    for (int n = 0; n < 4; ++n) {
      int row0 = qi * 128 + wr * 64 + m * 16 + ((lane >> 4) << 2);
      int col  = ki * 128 + wc * 64 + n * 16 + (lane & 15);
#pragma unroll
      for (int r = 0; r < 4; ++r) {
        int row = row0 + r;
        float v = (col > row) ? -1e9f : acc[m][n][r];
        Sb[(size_t)row * LQ + col] = f2bf(v);
      }
    }
}

// ---------------- K3: fused online-softmax + PV --------------------------
// Block: 512 thr / 8 waves (4M x 2N), out tile 128 rows x 256 cols.
// A = raw S tile (bf16, masked) staged in LDS; transformed in-register to
// P = exp(S - m) in A-frag layout; B = Vt tile staged in LDS.
// Online stats per row live on lanes with (lane&15)==row-in-frag.
__global__ __launch_bounds__(512, 2) void k_pv2(
    const u16* __restrict__ S, const u16* __restrict__ Vt,
    float* __restrict__ out, int bstart, int bcount)
{
  __shared__ __align__(16) u16 lds[49152];  // [2 bufs][A 8192 | B 16384] u16 = 96KB
  int bi = blockIdx.x;
  int per = 2 * bcount;
  int idx = bi / per;
  int rem = bi - idx * per;
  int rt = 31 - idx;                 // heavy-first
  int ct = rem / bcount;
  int b_local = rem - ct * bcount;
  int bg = bstart + b_local;
  int kIters = 2 * (rt + 1);

  const u16* Ap = S + ((size_t)b_local * LQ + rt * 128) * LQ;
  const u16* Bp = Vt + ((size_t)bg * EMB + ct * 256) * LQ;

  int tid = threadIdx.x, lane = tid & 63, wave = tid >> 6;
  int wr = wave >> 1, wc = wave & 1;  // 4M x 2N
  int l15 = lane & 15, lhi = lane >> 4;

  f32x4 acc[2][8];
#pragma unroll
  for (int m = 0; m < 2; ++m)
#pragma unroll
    for (int n = 0; n < 8; ++n) acc[m][n] = (f32x4)0.0f;
  float mrun[2] = {-3.0e38f, -3.0e38f};
  float lrun[2] = {0.f, 0.f};

  // prologue stage into buf0
  {
#pragma unroll
    for (int p = 0; p < 2; ++p) {    // A: 1024 chunks, 2/thread
      int c = tid + p * 512;
      int row = c >> 3, hh = c & 7;
      int h = hh ^ (row & 7);
      __builtin_amdgcn_global_load_lds((gas_ptr)(const void*)(Ap + (size_t)row * LQ + h * 8),
                                       (las_ptr)(void*)(lds + wave * 512 + p * 4096), 16, 0, 0);
    }
#pragma unroll
    for (int p = 0; p < 4; ++p) {    // B: 2048 chunks, 4/thread
      int c = tid + p * 512;
      int row = c >> 3, hh = c & 7;
      int h = hh ^ (row & 7);
      __builtin_amdgcn_global_load_lds((gas_ptr)(const void*)(Bp + (size_t)row * LQ + h * 8),
                                       (las_ptr)(void*)(lds + 8192 + wave * 512 + p * 4096), 16, 0, 0);
    }
  }

  for (int kb = 0; kb < kIters; ++kb) {
    u16* ldsA = lds + (kb & 1) * 24576;
    u16* ldsB = ldsA + 8192;
    __syncthreads();
    if (kb + 1 < kIters) {
      u16* nA = lds + ((kb + 1) & 1) * 24576;
      const u16* ga = Ap + (kb + 1) * 64;
      const u16* gb = Bp + (kb + 1) * 64;
#pragma unroll
      for (int p = 0; p < 2; ++p) {
        int c = tid + p * 512;
        int row = c >> 3, hh = c & 7;
        int h = hh ^ (row & 7);
        __builtin_amdgcn_global_load_lds((gas_ptr)(const void*)(ga + (size_t)row * LQ + h * 8),
                                         (las_ptr)(void*)(nA + wave * 512 + p * 4096), 16, 0, 0);
      }
#pragma unroll
      for (int p = 0; p < 4; ++p) {
        int c = tid + p * 512;
        int row = c >> 3, hh = c & 7;
        int h = hh ^ (row & 7);
        __builtin_amdgcn_global_load_lds((gas_ptr)(const void*)(gb + (size_t)row * LQ + h * 8),
                                         (las_ptr)(void*)(nA + 8192 + wave * 512 + p * 4096), 16, 0, 0);
      }
    }

    // --- read S frags (A layout), to float
    float sv[2][16];
#pragma unroll
    for (int m = 0; m < 2; ++m) {
      int row = wr * 32 + m * 16 + l15;
#pragma unroll
      for (int s = 0; s < 2; ++s) {
        int hh = (s * 4 + lhi) ^ (row & 7);
        u16x8 raw = *(const u16x8*)(ldsA + row * 64 + hh * 8);
#pragma unroll
        for (int j = 0; j < 8; ++j) sv[m][s * 8 + j] = bf2f(raw[j]);
      }
    }
    // --- tile row-max (rows split over lanes {r, r+16, r+32, r+48})
    float tmax[2];
#pragma unroll
    for (int m = 0; m < 2; ++m) {
      float tm = sv[m][0];
#pragma unroll
      for (int k = 1; k < 16; ++k) tm = fmaxf(tm, sv[m][k]);
      tm = fmaxf(tm, __shfl_xor(tm, 16));
      tm = fmaxf(tm, __shfl_xor(tm, 32));
      tmax[m] = tm;
    }
    // --- defer-max rescale (THR=8)
    bool need = (tmax[0] > mrun[0] + 8.f) || (tmax[1] > mrun[1] + 8.f);
    if (__any(need)) {
#pragma unroll
      for (int m = 0; m < 2; ++m) {
        float mn = fmaxf(mrun[m], tmax[m]);
        float f = __expf(mrun[m] - mn);
        mrun[m] = mn;
        lrun[m] *= f;
#pragma unroll
        for (int r = 0; r < 4; ++r) {
          float fr = __shfl(f, lhi * 4 + r);
#pragma unroll
          for (int n = 0; n < 8; ++n) acc[m][n][r] *= fr;
        }
      }
    }
    // --- P = exp(S - mrun), row sums, pack bf16 (stays in A-frag layout)
    u16x8 pf[2][2];
#pragma unroll
    for (int m = 0; m < 2; ++m) {
      float ts = 0.f;
#pragma unroll
      for (int s = 0; s < 2; ++s)
#pragma unroll
        for (int j = 0; j < 8; ++j) {
          float p = __expf(sv[m][s * 8 + j] - mrun[m]);
          ts += p;
          pf[m][s][j] = f2bf(p);
        }
      ts += __shfl_xor(ts, 16);
      ts += __shfl_xor(ts, 32);
      lrun[m] += ts;
    }
    // --- PV MFMA
#pragma unroll
    for (int s = 0; s < 2; ++s) {
#pragma unroll
      for (int n = 0; n < 8; ++n) {
        int col = wc * 128 + n * 16 + l15;
        int hh = (s * 4 + lhi) ^ (col & 7);
        bf16x8 bv = *(const bf16x8*)(ldsB + col * 64 + hh * 8);
#pragma unroll
        for (int m = 0; m < 2; ++m)
          acc[m][n] = __builtin_amdgcn_mfma_f32_16x16x32_bf16(
              __builtin_bit_cast(bf16x8, pf[m][s]), bv, acc[m][n], 0, 0, 0);
      }
    }
  }

  // --- epilogue: normalize by running sum, store fp32
#pragma unroll
  for (int m = 0; m < 2; ++m) {
    float linv = 1.0f / lrun[m];
#pragma unroll
    for (int r = 0; r < 4; ++r) {
      float fr = __shfl(linv, lhi * 4 + r);
      int grow = rt * 128 + wr * 32 + m * 16 + lhi * 4 + r;
#pragma unroll
      for (int n = 0; n < 8; ++n) {
        int col = ct * 256 + wc * 128 + n * 16 + l15;
        out[((size_t)bg * LQ + grow) * EMB + col] = acc[m][n][r] * fr;
      }
    }
  }
}

// ---------------- host ----------------------------------------------------
extern "C" void kernel_launch(void* const* d_in, const int* in_sizes, int n_in,
                              void* d_out, int out_size, void* d_ws, size_t ws_size,
                              hipStream_t stream) {
  const float* x  = (const float*)d_in[0];
  const float* Wq = (const float*)d_in[1];
  const float* bq = (const float*)d_in[2];
  const float* Wk = (const float*)d_in[3];
  const float* bk = (const float*)d_in[4];
  const float* Wv = (const float*)d_in[5];
  const float* bv = (const float*)d_in[6];

  char* ws = (char*)d_ws;
  size_t off = 0;
  u16* xb  = (u16*)(ws + off); off += (size_t)MROWS * EMB * 2;
  u16* wqb = (u16*)(ws + off); off += (size_t)EMB * EMB * 2;
  u16* wkb = (u16*)(ws + off); off += (size_t)EMB * EMB * 2;
  u16* wvb = (u16*)(ws + off); off += (size_t)EMB * EMB * 2;
  float* bias = (float*)(ws + off); off += 3 * EMB * 4;
  off = (off + 255) & ~(size_t)255;
  u16* Qb  = (u16*)(ws + off); off += (size_t)MROWS * EMB * 2;
  u16* Kb  = (u16*)(ws + off); off += (size_t)MROWS * EMB * 2;
  u16* Vtb = (u16*)(ws + off); off += (size_t)MROWS * EMB * 2;
  size_t fixed = off;
  size_t s_full = (size_t)NB * LQ * LQ * 2;
  int bcap = (ws_size >= fixed + s_full) ? NB : 1;
  u16* Sb = (u16*)(ws + fixed);

  prep_w<<<(EMB * EMB + 255) / 256, 256, 0, stream>>>(Wq, bq, Wk, bk, Wv, bv,
                                                      wqb, wkb, wvb, bias);
  prep_x<<<(MROWS * EMB / 8) / 256, 256, 0, stream>>>(x, xb);

  k_qkv<<<1536, 256, 0, stream>>>(xb, wqb, wkb, wvb, bias, Qb, Kb, Vtb);

  for (int bs = 0; bs < NB; bs += bcap) {
    int bc = (bs + bcap <= NB) ? bcap : (NB - bs);
    k_qk<<<528 * bc, 256, 0, stream>>>(Qb, Kb, Sb, bs);
    k_pv2<<<64 * bc, 512, 0, stream>>>(Sb, Vtb, (float*)d_out, bs, bc);
  }
}

// Round 4
// 244.696 us; speedup vs baseline: 1.0510x; 1.0510x over previous
//
#include <hip/hip_runtime.h>

typedef unsigned short u16;
typedef unsigned int u32;
typedef short bf16x8 __attribute__((ext_vector_type(8)));
typedef float f32x4 __attribute__((ext_vector_type(4)));
typedef u16 u16x8 __attribute__((ext_vector_type(8)));
typedef u16 u16x4 __attribute__((ext_vector_type(4)));

typedef const __attribute__((address_space(1))) u32* gas_ptr;
typedef __attribute__((address_space(3))) u32* las_ptr;

#define LQ   4096
#define EMB  512
#define NB   4
#define MROWS (NB * LQ)            // 16384
#define QSCALE 0.04419417382415922f // 1/sqrt(512)

__device__ __forceinline__ u16 f2bf(float f) {
  unsigned u = __builtin_bit_cast(unsigned, f);
  u += 0x7fffu + ((u >> 16) & 1u);
  return (u16)(u >> 16);
}
__device__ __forceinline__ float bf2f(u16 h) {
  unsigned u = ((unsigned)h) << 16;
  return __builtin_bit_cast(float, u);
}

// ---------------- prep ----------------------------------------------------
__global__ void prep_w(const float* __restrict__ Wq, const float* __restrict__ bq,
                       const float* __restrict__ Wk, const float* __restrict__ bk,
                       const float* __restrict__ Wv, const float* __restrict__ bv,
                       u16* __restrict__ wqb, u16* __restrict__ wkb, u16* __restrict__ wvb,
                       float* __restrict__ bias) {
  int i = blockIdx.x * 256 + threadIdx.x;
  if (i < EMB * EMB) {
    wqb[i] = f2bf(Wq[i] * QSCALE);
    wkb[i] = f2bf(Wk[i]);
    wvb[i] = f2bf(Wv[i]);
  }
  if (i < EMB) {
    bias[i]           = bq[i] * QSCALE;
    bias[EMB + i]     = bk[i];
    bias[2 * EMB + i] = bv[i];
  }
}

__global__ void prep_x(const float* __restrict__ x, u16* __restrict__ xb) {
  int i = blockIdx.x * 256 + threadIdx.x;
  const float4* p = (const float4*)(x + (size_t)i * 8);
  float4 a = p[0], b = p[1];
  u16x8 o;
  o[0] = f2bf(a.x); o[1] = f2bf(a.y); o[2] = f2bf(a.z); o[3] = f2bf(a.w);
  o[4] = f2bf(b.x); o[5] = f2bf(b.y); o[6] = f2bf(b.z); o[7] = f2bf(b.w);
  *(u16x8*)(xb + (size_t)i * 8) = o;
}

// ---- stage one 128x64 bf16 tile (16KB) with 256 threads, gload_lds w=16 ---
__device__ __forceinline__ void stage128_256t(const u16* g, int ld, u16* lds, int tid) {
  int wave = tid >> 6;
#pragma unroll
  for (int p = 0; p < 4; ++p) {
    int c = tid + p * 256;           // chunk 0..1023
    int row = c >> 3, hh = c & 7;
    int h = hh ^ (row & 7);
    const u16* src = g + (size_t)row * ld + h * 8;
    u16* dst = lds + wave * 512 + p * 2048;
    __builtin_amdgcn_global_load_lds((gas_ptr)(const void*)src, (las_ptr)(void*)dst, 16, 0, 0);
  }
}

// ---- 128x128 GEMM core, dbuf + prefetch ----------------------------------
__device__ __forceinline__ void gemm_core_db(
    const u16* __restrict__ A, int lda,
    const u16* __restrict__ B, int ldb,
    int kIters, u16* lds,
    f32x4 acc[4][4], int tid, int lane, int wr, int wc)
{
  stage128_256t(A, lda, lds, tid);
  stage128_256t(B, ldb, lds + 8192, tid);
  for (int kb = 0; kb < kIters; ++kb) {
    u16* ldsA = lds + (kb & 1) * 16384;
    u16* ldsB = ldsA + 8192;
    __syncthreads();
    if (kb + 1 < kIters) {
      u16* nA = lds + ((kb + 1) & 1) * 16384;
      stage128_256t(A + (kb + 1) * 64, lda, nA, tid);
      stage128_256t(B + (kb + 1) * 64, ldb, nA + 8192, tid);
    }
#pragma unroll
    for (int s = 0; s < 2; ++s) {
      bf16x8 af[4], bfr[4];
#pragma unroll
      for (int m = 0; m < 4; ++m) {
        int row = wr * 64 + m * 16 + (lane & 15);
        int hh = (s * 4 + (lane >> 4)) ^ (row & 7);
        af[m] = *(const bf16x8*)(ldsA + row * 64 + hh * 8);
      }
#pragma unroll
      for (int n = 0; n < 4; ++n) {
        int row = wc * 64 + n * 16 + (lane & 15);
        int hh = (s * 4 + (lane >> 4)) ^ (row & 7);
        bfr[n] = *(const bf16x8*)(ldsB + row * 64 + hh * 8);
      }
#pragma unroll
      for (int m = 0; m < 4; ++m)
#pragma unroll
        for (int n = 0; n < 4; ++n)
          acc[m][n] = __builtin_amdgcn_mfma_f32_16x16x32_bf16(af[m], bfr[n], acc[m][n], 0, 0, 0);
    }
  }
}

// ---------------- K1: fused QKV projection GEMM --------------------------
__global__ __launch_bounds__(256, 2) void k_qkv(
    const u16* __restrict__ xb,
    const u16* __restrict__ w0, const u16* __restrict__ w1, const u16* __restrict__ w2,
    const float* __restrict__ bias,
    u16* __restrict__ o0, u16* __restrict__ o1, u16* __restrict__ o2)
{
  __shared__ __align__(16) u16 lds[32768];
  int bi = blockIdx.x;
  int which = bi >> 9;
  int t = bi & 511;
  int rt = t >> 2, ct = t & 3;
  const u16* W = (which == 0) ? w0 : (which == 1) ? w1 : w2;
  const float* bs = bias + which * EMB;
  int tid = threadIdx.x, lane = tid & 63, wave = tid >> 6;
  int wr = wave >> 1, wc = wave & 1;
  f32x4 acc[4][4];
#pragma unroll
  for (int m = 0; m < 4; ++m)
#pragma unroll
    for (int n = 0; n < 4; ++n) acc[m][n] = (f32x4)0.0f;

  gemm_core_db(xb + (size_t)rt * 128 * EMB, EMB,
               W + (size_t)ct * 128 * EMB, EMB, EMB / 64,
               lds, acc, tid, lane, wr, wc);

#pragma unroll
  for (int m = 0; m < 4; ++m)
#pragma unroll
    for (int n = 0; n < 4; ++n) {
      int row0 = rt * 128 + wr * 64 + m * 16 + ((lane >> 4) << 2);
      int col  = ct * 128 + wc * 64 + n * 16 + (lane & 15);
      float bv = bs[col];
      if (which < 2) {
        u16* out = (which == 0) ? o0 : o1;
#pragma unroll
        for (int r = 0; r < 4; ++r)
          out[(size_t)(row0 + r) * EMB + col] = f2bf(acc[m][n][r] + bv);
      } else {
        int b = row0 >> 12, l0 = row0 & (LQ - 1);
        u16x4 pk;
#pragma unroll
        for (int r = 0; r < 4; ++r) pk[r] = f2bf(acc[m][n][r] + bv);
        *(u16x4*)(o2 + ((size_t)(b * EMB + col)) * LQ + l0) = pk;
      }
    }
}

// ---------------- K2: S = Q K^T on causal (lower-tri) tiles --------------
__global__ __launch_bounds__(256, 2) void k_qk(
    const u16* __restrict__ Q, const u16* __restrict__ K,
    u16* __restrict__ S, int bstart)
{
  __shared__ __align__(16) u16 lds[32768];
  int t = blockIdx.x;
  int b_local = t / 528;
  int i = t - b_local * 528;
  int qi = (int)((sqrtf(8.f * (float)i + 1.f) - 1.f) * 0.5f);
  while ((qi + 1) * (qi + 2) / 2 <= i) ++qi;
  while (qi * (qi + 1) / 2 > i) --qi;
  int ki = i - qi * (qi + 1) / 2;
  int bg = bstart + b_local;

  int tid = threadIdx.x, lane = tid & 63, wave = tid >> 6;
  int wr = wave >> 1, wc = wave & 1;
  f32x4 acc[4][4];
#pragma unroll
  for (int m = 0; m < 4; ++m)
#pragma unroll
    for (int n = 0; n < 4; ++n) acc[m][n] = (f32x4)0.0f;

  gemm_core_db(Q + ((size_t)bg * LQ + qi * 128) * EMB, EMB,
               K + ((size_t)bg * LQ + ki * 128) * EMB, EMB, EMB / 64,
               lds, acc, tid, lane, wr, wc);

  u16* Sb = S + (size_t)b_local * LQ * LQ;
#pragma unroll
  for (int m = 0; m < 4; ++m)
#pragma unroll
    for (int n = 0; n < 4; ++n) {
      int row0 = qi * 128 + wr * 64 + m * 16 + ((lane >> 4) << 2);
      int col  = ki * 128 + wc * 64 + n * 16 + (lane & 15);
#pragma unroll
      for (int r = 0; r < 4; ++r) {
        int row = row0 + r;
        float v = (col > row) ? -1e9f : acc[m][n][r];
        Sb[(size_t)row * LQ + col] = f2bf(v);
      }
    }
}

// ---------------- K3: fused online-softmax + PV, PAIRED row-tiles --------
// Each block handles rt_a = pairidx and rt_b = 31-pairidx sequentially:
// uniform 66 K-units of 64 per block -> zero load imbalance at 1 block/CU.
// 512 thr / 8 waves (4M x 2N), out 128 rows x 128 cols per phase.
// LDS: [2 bufs][A 8192 | B 8192] u16 = 64 KB.
__global__ __launch_bounds__(512, 1) void k_pv2(
    const u16* __restrict__ S, const u16* __restrict__ Vt,
    float* __restrict__ out, int bstart, int bcount)
{
  __shared__ __align__(16) u16 lds[32768];
  int bi = blockIdx.x;
  int per = 4 * bcount;
  int pairidx = bi / per;
  int rem = bi - pairidx * per;
  int ct = rem / bcount;
  int b_local = rem - ct * bcount;
  int bg = bstart + b_local;

  int rtA = pairidx, rtB = 31 - pairidx;
  int unitsA = 2 * (rtA + 1);
  int total = unitsA + 2 * (rtB + 1);       // == 66

  const u16* Sbase = S + (size_t)b_local * LQ * LQ;
  const u16* Bp = Vt + ((size_t)bg * EMB + ct * 128) * LQ;

  int tid = threadIdx.x, lane = tid & 63, wave = tid >> 6;
  int wr = wave >> 2, wc = wave & 3;        // placeholder; real mapping below
  // 8 waves as 4 row-groups x 2 col-groups:
  wr = wave >> 1; wc = wave & 1;
  int l15 = lane & 15, lhi = lane >> 4;

  f32x4 acc[2][4];
#pragma unroll
  for (int m = 0; m < 2; ++m)
#pragma unroll
    for (int n = 0; n < 4; ++n) acc[m][n] = (f32x4)0.0f;
  float mrun[2] = {-3.0e38f, -3.0e38f};
  float lrun[2] = {0.f, 0.f};

  // stage unit i into buffer (i&1). 512 thr: A 1024 chunks (2/thr), B 1024 (2/thr).
  auto stage_unit = [&](int i) {
    int ph = (i >= unitsA);
    int kb = ph ? (i - unitsA) : i;
    int rt = ph ? rtB : rtA;
    const u16* ga = Sbase + ((size_t)rt * 128) * LQ + kb * 64;
    const u16* gb = Bp + kb * 64;
    u16* buf = lds + (i & 1) * 16384;
#pragma unroll
    for (int p = 0; p < 2; ++p) {
      int c = tid + p * 512;
      int row = c >> 3, hh = c & 7;
      int h = hh ^ (row & 7);
      __builtin_amdgcn_global_load_lds((gas_ptr)(const void*)(ga + (size_t)row * LQ + h * 8),
                                       (las_ptr)(void*)(buf + wave * 512 + p * 4096), 16, 0, 0);
      __builtin_amdgcn_global_load_lds((gas_ptr)(const void*)(gb + (size_t)row * LQ + h * 8),
                                       (las_ptr)(void*)(buf + 8192 + wave * 512 + p * 4096), 16, 0, 0);
    }
  };

  auto epilogue = [&](int rt) {
#pragma unroll
    for (int m = 0; m < 2; ++m) {
      float linv = 1.0f / lrun[m];
#pragma unroll
      for (int r = 0; r < 4; ++r) {
        float fr = __shfl(linv, lhi * 4 + r);
        int grow = rt * 128 + wr * 32 + m * 16 + lhi * 4 + r;
#pragma unroll
        for (int n = 0; n < 4; ++n) {
          int col = ct * 128 + wc * 64 + n * 16 + l15;
          out[((size_t)bg * LQ + grow) * EMB + col] = acc[m][n][r] * fr;
        }
      }
    }
#pragma unroll
    for (int m = 0; m < 2; ++m) {
#pragma unroll
      for (int n = 0; n < 4; ++n) acc[m][n] = (f32x4)0.0f;
      mrun[m] = -3.0e38f;
      lrun[m] = 0.f;
    }
  };

  stage_unit(0);

  for (int i = 0; i < total; ++i) {
    u16* ldsA = lds + (i & 1) * 16384;
    u16* ldsB = ldsA + 8192;
    __syncthreads();
    if (i + 1 < total) stage_unit(i + 1);
    if (i == unitsA) epilogue(rtA);          // flush phase A, reset stats

    // --- read S frags (A layout) to float
    float sv[2][16];
#pragma unroll
    for (int m = 0; m < 2; ++m) {
      int row = wr * 32 + m * 16 + l15;
#pragma unroll
      for (int s = 0; s < 2; ++s) {
        int hh = (s * 4 + lhi) ^ (row & 7);
        u16x8 raw = *(const u16x8*)(ldsA + row * 64 + hh * 8);
#pragma unroll
        for (int j = 0; j < 8; ++j) sv[m][s * 8 + j] = bf2f(raw[j]);
      }
    }
    // --- tile row-max
    float tmax[2];
#pragma unroll
    for (int m = 0; m < 2; ++m) {
      float tm = sv[m][0];
#pragma unroll
      for (int k = 1; k < 16; ++k) tm = fmaxf(tm, sv[m][k]);
      tm = fmaxf(tm, __shfl_xor(tm, 16));
      tm = fmaxf(tm, __shfl_xor(tm, 32));
      tmax[m] = tm;
    }
    // --- defer-max rescale (THR=8)
    bool need = (tmax[0] > mrun[0] + 8.f) || (tmax[1] > mrun[1] + 8.f);
    if (__any(need)) {
#pragma unroll
      for (int m = 0; m < 2; ++m) {
        float mn = fmaxf(mrun[m], tmax[m]);
        float f = __expf(mrun[m] - mn);
        mrun[m] = mn;
        lrun[m] *= f;
#pragma unroll
        for (int r = 0; r < 4; ++r) {
          float fr = __shfl(f, lhi * 4 + r);
#pragma unroll
          for (int n = 0; n < 4; ++n) acc[m][n][r] *= fr;
        }
      }
    }
    // --- P = exp(S - mrun), row sums, pack bf16 (A-frag layout)
    u16x8 pf[2][2];
#pragma unroll
    for (int m = 0; m < 2; ++m) {
      float ts = 0.f;
#pragma unroll
      for (int s = 0; s < 2; ++s)
#pragma unroll
        for (int j = 0; j < 8; ++j) {
          float p = __expf(sv[m][s * 8 + j] - mrun[m]);
          ts += p;
          pf[m][s][j] = f2bf(p);
        }
      ts += __shfl_xor(ts, 16);
      ts += __shfl_xor(ts, 32);
      lrun[m] += ts;
    }
    // --- PV MFMA
#pragma unroll
    for (int s = 0; s < 2; ++s) {
#pragma unroll
      for (int n = 0; n < 4; ++n) {
        int col = wc * 64 + n * 16 + l15;
        int hh = (s * 4 + lhi) ^ (col & 7);
        bf16x8 bv = *(const bf16x8*)(ldsB + col * 64 + hh * 8);
#pragma unroll
        for (int m = 0; m < 2; ++m)
          acc[m][n] = __builtin_amdgcn_mfma_f32_16x16x32_bf16(
              __builtin_bit_cast(bf16x8, pf[m][s]), bv, acc[m][n], 0, 0, 0);
      }
    }
  }
  epilogue(rtB);
}

// ---------------- host ----------------------------------------------------
extern "C" void kernel_launch(void* const* d_in, const int* in_sizes, int n_in,
                              void* d_out, int out_size, void* d_ws, size_t ws_size,
                              hipStream_t stream) {
  const float* x  = (const float*)d_in[0];
  const float* Wq = (const float*)d_in[1];
  const float* bq = (const float*)d_in[2];
  const float* Wk = (const float*)d_in[3];
  const float* bk = (const float*)d_in[4];
  const float* Wv = (const float*)d_in[5];
  const float* bv = (const float*)d_in[6];

  char* ws = (char*)d_ws;
  size_t off = 0;
  u16* xb  = (u16*)(ws + off); off += (size_t)MROWS * EMB * 2;
  u16* wqb = (u16*)(ws + off); off += (size_t)EMB * EMB * 2;
  u16* wkb = (u16*)(ws + off); off += (size_t)EMB * EMB * 2;
  u16* wvb = (u16*)(ws + off); off += (size_t)EMB * EMB * 2;
  float* bias = (float*)(ws + off); off += 3 * EMB * 4;
  off = (off + 255) & ~(size_t)255;
  u16* Qb  = (u16*)(ws + off); off += (size_t)MROWS * EMB * 2;
  u16* Kb  = (u16*)(ws + off); off += (size_t)MROWS * EMB * 2;
  u16* Vtb = (u16*)(ws + off); off += (size_t)MROWS * EMB * 2;
  size_t fixed = off;
  size_t s_full = (size_t)NB * LQ * LQ * 2;
  int bcap = (ws_size >= fixed + s_full) ? NB : 1;
  u16* Sb = (u16*)(ws + fixed);

  prep_w<<<(EMB * EMB + 255) / 256, 256, 0, stream>>>(Wq, bq, Wk, bk, Wv, bv,
                                                      wqb, wkb, wvb, bias);
  prep_x<<<(MROWS * EMB / 8) / 256, 256, 0, stream>>>(x, xb);

  k_qkv<<<1536, 256, 0, stream>>>(xb, wqb, wkb, wvb, bias, Qb, Kb, Vtb);

  for (int bs = 0; bs < NB; bs += bcap) {
    int bc = (bs + bcap <= NB) ? bcap : (NB - bs);
    k_qk<<<528 * bc, 256, 0, stream>>>(Qb, Kb, Sb, bs);
    k_pv2<<<64 * bc, 512, 0, stream>>>(Sb, Vtb, (float*)d_out, bs, bc);
  }
}

// Round 5
// 244.429 us; speedup vs baseline: 1.0521x; 1.0011x over previous
//
#include <hip/hip_runtime.h>

typedef unsigned short u16;
typedef unsigned int u32;
typedef short bf16x8 __attribute__((ext_vector_type(8)));
typedef float f32x4 __attribute__((ext_vector_type(4)));
typedef u16 u16x8 __attribute__((ext_vector_type(8)));
typedef u16 u16x4 __attribute__((ext_vector_type(4)));

typedef const __attribute__((address_space(1))) u32* gas_ptr;
typedef __attribute__((address_space(3))) u32* las_ptr;

#define LQ   4096
#define EMB  512
#define NB   4
#define MROWS (NB * LQ)            // 16384
#define QSCALE 0.04419417382415922f // 1/sqrt(512)

__device__ __forceinline__ u16 f2bf(float f) {
  unsigned u = __builtin_bit_cast(unsigned, f);
  u += 0x7fffu + ((u >> 16) & 1u);
  return (u16)(u >> 16);
}
__device__ __forceinline__ float bf2f(u16 h) {
  unsigned u = ((unsigned)h) << 16;
  return __builtin_bit_cast(float, u);
}

// ---------------- prep ----------------------------------------------------
__global__ void prep_w(const float* __restrict__ Wq, const float* __restrict__ bq,
                       const float* __restrict__ Wk, const float* __restrict__ bk,
                       const float* __restrict__ Wv, const float* __restrict__ bv,
                       u16* __restrict__ wqb, u16* __restrict__ wkb, u16* __restrict__ wvb,
                       float* __restrict__ bias) {
  int i = blockIdx.x * 256 + threadIdx.x;
  if (i < EMB * EMB) {
    wqb[i] = f2bf(Wq[i] * QSCALE);
    wkb[i] = f2bf(Wk[i]);
    wvb[i] = f2bf(Wv[i]);
  }
  if (i < EMB) {
    bias[i]           = bq[i] * QSCALE;
    bias[EMB + i]     = bk[i];
    bias[2 * EMB + i] = bv[i];
  }
}

__global__ void prep_x(const float* __restrict__ x, u16* __restrict__ xb) {
  int i = blockIdx.x * 256 + threadIdx.x;
  const float4* p = (const float4*)(x + (size_t)i * 8);
  float4 a = p[0], b = p[1];
  u16x8 o;
  o[0] = f2bf(a.x); o[1] = f2bf(a.y); o[2] = f2bf(a.z); o[3] = f2bf(a.w);
  o[4] = f2bf(b.x); o[5] = f2bf(b.y); o[6] = f2bf(b.z); o[7] = f2bf(b.w);
  *(u16x8*)(xb + (size_t)i * 8) = o;
}

// ---- stage one 128x64 bf16 tile (16KB) with 256 threads, gload_lds w=16 ---
__device__ __forceinline__ void stage128_256t(const u16* g, int ld, u16* lds, int tid) {
  int wave = tid >> 6;
#pragma unroll
  for (int p = 0; p < 4; ++p) {
    int c = tid + p * 256;           // chunk 0..1023
    int row = c >> 3, hh = c & 7;
    int h = hh ^ (row & 7);
    const u16* src = g + (size_t)row * ld + h * 8;
    u16* dst = lds + wave * 512 + p * 2048;
    __builtin_amdgcn_global_load_lds((gas_ptr)(const void*)src, (las_ptr)(void*)dst, 16, 0, 0);
  }
}

// ---- 128x128 GEMM core, dbuf + prefetch ----------------------------------
__device__ __forceinline__ void gemm_core_db(
    const u16* __restrict__ A, int lda,
    const u16* __restrict__ B, int ldb,
    int kIters, u16* lds,
    f32x4 acc[4][4], int tid, int lane, int wr, int wc)
{
  stage128_256t(A, lda, lds, tid);
  stage128_256t(B, ldb, lds + 8192, tid);
  for (int kb = 0; kb < kIters; ++kb) {
    u16* ldsA = lds + (kb & 1) * 16384;
    u16* ldsB = ldsA + 8192;
    __syncthreads();
    if (kb + 1 < kIters) {
      u16* nA = lds + ((kb + 1) & 1) * 16384;
      stage128_256t(A + (kb + 1) * 64, lda, nA, tid);
      stage128_256t(B + (kb + 1) * 64, ldb, nA + 8192, tid);
    }
#pragma unroll
    for (int s = 0; s < 2; ++s) {
      bf16x8 af[4], bfr[4];
#pragma unroll
      for (int m = 0; m < 4; ++m) {
        int row = wr * 64 + m * 16 + (lane & 15);
        int hh = (s * 4 + (lane >> 4)) ^ (row & 7);
        af[m] = *(const bf16x8*)(ldsA + row * 64 + hh * 8);
      }
#pragma unroll
      for (int n = 0; n < 4; ++n) {
        int row = wc * 64 + n * 16 + (lane & 15);
        int hh = (s * 4 + (lane >> 4)) ^ (row & 7);
        bfr[n] = *(const bf16x8*)(ldsB + row * 64 + hh * 8);
      }
#pragma unroll
      for (int m = 0; m < 4; ++m)
#pragma unroll
        for (int n = 0; n < 4; ++n)
          acc[m][n] = __builtin_amdgcn_mfma_f32_16x16x32_bf16(af[m], bfr[n], acc[m][n], 0, 0, 0);
    }
  }
}

// ---------------- K1: fused QKV projection GEMM --------------------------
__global__ __launch_bounds__(256, 2) void k_qkv(
    const u16* __restrict__ xb,
    const u16* __restrict__ w0, const u16* __restrict__ w1, const u16* __restrict__ w2,
    const float* __restrict__ bias,
    u16* __restrict__ o0, u16* __restrict__ o1, u16* __restrict__ o2)
{
  __shared__ __align__(16) u16 lds[32768];
  int bi = blockIdx.x;
  int which = bi >> 9;
  int t = bi & 511;
  int rt = t >> 2, ct = t & 3;
  const u16* W = (which == 0) ? w0 : (which == 1) ? w1 : w2;
  const float* bs = bias + which * EMB;
  int tid = threadIdx.x, lane = tid & 63, wave = tid >> 6;
  int wr = wave >> 1, wc = wave & 1;
  f32x4 acc[4][4];
#pragma unroll
  for (int m = 0; m < 4; ++m)
#pragma unroll
    for (int n = 0; n < 4; ++n) acc[m][n] = (f32x4)0.0f;

  gemm_core_db(xb + (size_t)rt * 128 * EMB, EMB,
               W + (size_t)ct * 128 * EMB, EMB, EMB / 64,
               lds, acc, tid, lane, wr, wc);

#pragma unroll
  for (int m = 0; m < 4; ++m)
#pragma unroll
    for (int n = 0; n < 4; ++n) {
      int row0 = rt * 128 + wr * 64 + m * 16 + ((lane >> 4) << 2);
      int col  = ct * 128 + wc * 64 + n * 16 + (lane & 15);
      float bv = bs[col];
      if (which < 2) {
        u16* out = (which == 0) ? o0 : o1;
#pragma unroll
        for (int r = 0; r < 4; ++r)
          out[(size_t)(row0 + r) * EMB + col] = f2bf(acc[m][n][r] + bv);
      } else {
        int b = row0 >> 12, l0 = row0 & (LQ - 1);
        u16x4 pk;
#pragma unroll
        for (int r = 0; r < 4; ++r) pk[r] = f2bf(acc[m][n][r] + bv);
        *(u16x4*)(o2 + ((size_t)(b * EMB + col)) * LQ + l0) = pk;
      }
    }
}

// ---------------- K2: S = Q K^T on causal (lower-tri) tiles --------------
__global__ __launch_bounds__(256, 2) void k_qk(
    const u16* __restrict__ Q, const u16* __restrict__ K,
    u16* __restrict__ S, int bstart)
{
  __shared__ __align__(16) u16 lds[32768];
  int t = blockIdx.x;
  int b_local = t / 528;
  int i = t - b_local * 528;
  int qi = (int)((sqrtf(8.f * (float)i + 1.f) - 1.f) * 0.5f);
  while ((qi + 1) * (qi + 2) / 2 <= i) ++qi;
  while (qi * (qi + 1) / 2 > i) --qi;
  int ki = i - qi * (qi + 1) / 2;
  int bg = bstart + b_local;

  int tid = threadIdx.x, lane = tid & 63, wave = tid >> 6;
  int wr = wave >> 1, wc = wave & 1;
  f32x4 acc[4][4];
#pragma unroll
  for (int m = 0; m < 4; ++m)
#pragma unroll
    for (int n = 0; n < 4; ++n) acc[m][n] = (f32x4)0.0f;

  gemm_core_db(Q + ((size_t)bg * LQ + qi * 128) * EMB, EMB,
               K + ((size_t)bg * LQ + ki * 128) * EMB, EMB, EMB / 64,
               lds, acc, tid, lane, wr, wc);

  u16* Sb = S + (size_t)b_local * LQ * LQ;
#pragma unroll
  for (int m = 0; m < 4; ++m)
#pragma unroll
    for (int n = 0; n < 4; ++n) {
      int row0 = qi * 128 + wr * 64 + m * 16 + ((lane >> 4) << 2);
      int col  = ki * 128 + wc * 64 + n * 16 + (lane & 15);
#pragma unroll
      for (int r = 0; r < 4; ++r) {
        int row = row0 + r;
        float v = (col > row) ? -1e9f : acc[m][n][r];
        Sb[(size_t)row * LQ + col] = f2bf(v);
      }
    }
}

// ---------------- K3: fused online-softmax + PV, M=32 / N=512 -----------
// Softmax computed ONCE per S element (512 thr x 4 vals = 32x64 tile),
// P shared via LDS by all 8 waves; each wave owns 64 output cols.
// Row-tiles (32 rows) paired (rt, 127-rt): uniform 65 K-units per block.
// LDS: A dbuf 8K + V dbuf 128K + P 4K + stats ~140.4 KB -> 1 block/CU.
__global__ __launch_bounds__(512, 1) void k_pv2(
    const u16* __restrict__ S, const u16* __restrict__ Vt,
    float* __restrict__ out, int bstart, int bcount)
{
  __shared__ __align__(16) u16 sA[4096];     // 2 x [32][64]
  __shared__ __align__(16) u16 sB[65536];    // 2 x [512][64]
  __shared__ __align__(16) u16 sP[2048];     // [32][64]
  __shared__ float sF[32];                   // per-row rescale factor
  __shared__ float sL[32];                   // per-row 1/sum at epilogue

  int bi = blockIdx.x;
  int pairidx = bi / bcount;
  int b_local = bi - pairidx * bcount;
  int bg = bstart + b_local;
  int rtA = pairidx, rtB = 127 - pairidx;
  int unitsA = (rtA + 2) >> 1;
  int total = unitsA + ((rtB + 2) >> 1);     // == 65

  const u16* Sbase = S + (size_t)b_local * LQ * LQ;
  const u16* Vb = Vt + (size_t)bg * EMB * LQ;

  int tid = threadIdx.x, lane = tid & 63, wave = tid >> 6;
  int l15 = lane & 15, lhi = lane >> 4;
  int srow = tid >> 4;                       // softmax row 0..31
  int scg  = tid & 15;                       // 4-col granule within row
  int shh  = ((scg >> 1) ^ (srow & 7)) * 8 + (scg & 1) * 4;  // swizzled u16 offset

  f32x4 acc[2][4];
#pragma unroll
  for (int m = 0; m < 2; ++m)
#pragma unroll
    for (int n = 0; n < 4; ++n) acc[m][n] = (f32x4)0.0f;
  float mrun = -3.0e38f, lrun = 0.f;

  auto stage_unit = [&](int i) {
    int ph = (i >= unitsA) ? 1 : 0;
    int rt = ph ? rtB : rtA;
    int k0 = (ph ? (i - unitsA) : i) * 64;
    const u16* ga = Sbase + (size_t)(rt * 32) * LQ + k0;
    const u16* gb = Vb + k0;
    u16* bA = sA + (i & 1) * 2048;
    u16* bB = sB + (i & 1) * 32768;
    if (wave < 4) {                          // A: 256 granules, waves 0-3
      int ca = wave * 64 + lane;
      int row = ca >> 3, h = ca & 7;
      __builtin_amdgcn_global_load_lds(
          (gas_ptr)(const void*)(ga + (size_t)row * LQ + (h ^ (row & 7)) * 8),
          (las_ptr)(void*)(bA + wave * 512), 16, 0, 0);
    }
#pragma unroll
    for (int p = 0; p < 8; ++p) {            // B: 4096 granules, 8/wave
      int cb = wave * 512 + p * 64 + lane;
      int col = cb >> 3, h = cb & 7;
      __builtin_amdgcn_global_load_lds(
          (gas_ptr)(const void*)(gb + (size_t)col * LQ + (h ^ (col & 7)) * 8),
          (las_ptr)(void*)(bB + wave * 4096 + p * 512), 16, 0, 0);
    }
  };

  auto epilogue = [&](int rt) {
    // called right after a __syncthreads (prior MFMA done)
    if (scg == 0) sL[srow] = 1.0f / lrun;
    __syncthreads();
    float li[2][4];
#pragma unroll
    for (int m = 0; m < 2; ++m)
#pragma unroll
      for (int r = 0; r < 4; ++r) li[m][r] = sL[m * 16 + lhi * 4 + r];
#pragma unroll
    for (int m = 0; m < 2; ++m)
#pragma unroll
      for (int r = 0; r < 4; ++r) {
        int grow = rt * 32 + m * 16 + lhi * 4 + r;
#pragma unroll
        for (int n = 0; n < 4; ++n) {
          int col = wave * 64 + n * 16 + l15;
          out[((size_t)bg * LQ + grow) * EMB + col] = acc[m][n][r] * li[m][r];
        }
      }
#pragma unroll
    for (int m = 0; m < 2; ++m)
#pragma unroll
      for (int n = 0; n < 4; ++n) acc[m][n] = (f32x4)0.0f;
    mrun = -3.0e38f;
    lrun = 0.f;
  };

  stage_unit(0);

  for (int i = 0; i < total; ++i) {
    u16* bA = sA + (i & 1) * 2048;
    u16* bB = sB + (i & 1) * 32768;
    __syncthreads();                         // buffers i ready; prior MFMA done
    if (i + 1 < total) stage_unit(i + 1);
    if (i == unitsA) epilogue(rtA);          // flush phase A (block-uniform)

    // ---- softmax: this thread's 4 S values (row srow, cols scg*4..+3)
    u16x4 raw = *(const u16x4*)(bA + srow * 64 + shh);
    float s0 = bf2f(raw[0]), s1 = bf2f(raw[1]), s2 = bf2f(raw[2]), s3 = bf2f(raw[3]);
    float tmax = fmaxf(fmaxf(s0, s1), fmaxf(s2, s3));
#pragma unroll
    for (int off = 1; off <= 8; off <<= 1) tmax = fmaxf(tmax, __shfl_xor(tmax, off));
    float mnew = (tmax > mrun + 8.f) ? tmax : mrun;   // defer-max THR=8
    float f = __expf(mrun - mnew);                     // exactly 1.0 if unchanged
    mrun = mnew;
    float e0 = __expf(s0 - mrun), e1 = __expf(s1 - mrun);
    float e2 = __expf(s2 - mrun), e3 = __expf(s3 - mrun);
    float rs = (e0 + e1) + (e2 + e3);
#pragma unroll
    for (int off = 1; off <= 8; off <<= 1) rs += __shfl_xor(rs, off);
    lrun = lrun * f + rs;
    u16x4 pk;
    pk[0] = f2bf(e0); pk[1] = f2bf(e1); pk[2] = f2bf(e2); pk[3] = f2bf(e3);
    *(u16x4*)(sP + srow * 64 + shh) = pk;
    if (scg == 0) sF[srow] = f;
    __syncthreads();                         // P + sF ready

    // ---- rescale acc by per-row factor (f==1 when no max update)
    float fr[2][4];
#pragma unroll
    for (int m = 0; m < 2; ++m)
#pragma unroll
      for (int r = 0; r < 4; ++r) fr[m][r] = sF[m * 16 + lhi * 4 + r];
#pragma unroll
    for (int m = 0; m < 2; ++m)
#pragma unroll
      for (int n = 0; n < 4; ++n)
#pragma unroll
        for (int r = 0; r < 4; ++r) acc[m][n][r] *= fr[m][r];

    // ---- PV MFMA: all waves share P, each wave owns 64 cols of V
#pragma unroll
    for (int s = 0; s < 2; ++s) {
      bf16x8 af[2];
#pragma unroll
      for (int m = 0; m < 2; ++m) {
        int row = m * 16 + l15;
        int hh = (s * 4 + lhi) ^ (row & 7);
        af[m] = *(const bf16x8*)(sP + row * 64 + hh * 8);
      }
#pragma unroll
      for (int n = 0; n < 4; ++n) {
        int col = wave * 64 + n * 16 + l15;
        int hh = (s * 4 + lhi) ^ (col & 7);
        bf16x8 bv = *(const bf16x8*)(bB + col * 64 + hh * 8);
#pragma unroll
        for (int m = 0; m < 2; ++m)
          acc[m][n] = __builtin_amdgcn_mfma_f32_16x16x32_bf16(af[m], bv, acc[m][n], 0, 0, 0);
      }
    }
  }
  __syncthreads();                           // last MFMA done before sL write
  epilogue(rtB);
}

// ---------------- host ----------------------------------------------------
extern "C" void kernel_launch(void* const* d_in, const int* in_sizes, int n_in,
                              void* d_out, int out_size, void* d_ws, size_t ws_size,
                              hipStream_t stream) {
  const float* x  = (const float*)d_in[0];
  const float* Wq = (const float*)d_in[1];
  const float* bq = (const float*)d_in[2];
  const float* Wk = (const float*)d_in[3];
  const float* bk = (const float*)d_in[4];
  const float* Wv = (const float*)d_in[5];
  const float* bv = (const float*)d_in[6];

  char* ws = (char*)d_ws;
  size_t off = 0;
  u16* xb  = (u16*)(ws + off); off += (size_t)MROWS * EMB * 2;
  u16* wqb = (u16*)(ws + off); off += (size_t)EMB * EMB * 2;
  u16* wkb = (u16*)(ws + off); off += (size_t)EMB * EMB * 2;
  u16* wvb = (u16*)(ws + off); off += (size_t)EMB * EMB * 2;
  float* bias = (float*)(ws + off); off += 3 * EMB * 4;
  off = (off + 255) & ~(size_t)255;
  u16* Qb  = (u16*)(ws + off); off += (size_t)MROWS * EMB * 2;
  u16* Kb  = (u16*)(ws + off); off += (size_t)MROWS * EMB * 2;
  u16* Vtb = (u16*)(ws + off); off += (size_t)MROWS * EMB * 2;
  size_t fixed = off;
  size_t s_full = (size_t)NB * LQ * LQ * 2;
  int bcap = (ws_size >= fixed + s_full) ? NB : 1;
  u16* Sb = (u16*)(ws + fixed);

  prep_w<<<(EMB * EMB + 255) / 256, 256, 0, stream>>>(Wq, bq, Wk, bk, Wv, bv,
                                                      wqb, wkb, wvb, bias);
  prep_x<<<(MROWS * EMB / 8) / 256, 256, 0, stream>>>(x, xb);

  k_qkv<<<1536, 256, 0, stream>>>(xb, wqb, wkb, wvb, bias, Qb, Kb, Vtb);

  for (int bs = 0; bs < NB; bs += bcap) {
    int bc = (bs + bcap <= NB) ? bcap : (NB - bs);
    k_qk<<<528 * bc, 256, 0, stream>>>(Qb, Kb, Sb, bs);
    k_pv2<<<64 * bc, 512, 0, stream>>>(Sb, Vtb, (float*)d_out, bs, bc);
  }
}